// Round 4
// baseline (71.820 us; speedup 1.0000x reference)
//
#include <hip/hip_runtime.h>
#include <math.h>

#define H_   23
#define W_   23
#define P_   529
#define TH_  0.05f
#define NC   9            // ceil(529/64) chunks per wave
#define CAP  96           // max compacted peaks (geometric max is 64 for strict peaks)
#define WPB  4            // waves (batch elements) per block
#define NTHR (WPB * 64)
#define WFLO (2 * P_ + 112)  // floats per wave LDS partition

// wave-synchronous fence: per-wave LDS ops execute in program order across the
// whole wave (SIMD lockstep); this only stops compiler reordering across phases.
#define WSYNC() do { asm volatile("" ::: "memory"); __builtin_amdgcn_wave_barrier(); } while (0)

__global__ __launch_bounds__(NTHR, 8) void peak_kernel(
    const float* __restrict__ tscores,  // [2,B,P]
    const float* __restrict__ anno,     // [1,B,P]
    const float* __restrict__ W1, const float* __restrict__ b1,
    const float* __restrict__ g1, const float* __restrict__ be1,
    const float* __restrict__ m1, const float* __restrict__ v1,
    const float* __restrict__ W2, const float* __restrict__ b2,
    const float* __restrict__ g2, const float* __restrict__ be2,
    const float* __restrict__ m2, const float* __restrict__ v2,
    const float* __restrict__ W3, const float* __restrict__ b3,
    float* __restrict__ out, int B)
{
    const int t  = threadIdx.x;
    const int l  = t & 63;
    const int wv = t >> 6;
    const int b  = blockIdx.x * WPB + wv;

    __shared__ float lds[WPB * WFLO];
    float* m  = lds + wv * WFLO;   // [529] raw map (old, then cur — kept for out_s)
    float* r  = m + P_;            // [529] rowmax; later cs/cp/rk; later inv
    float* wt = r + P_;            // [112] folded MLP weights; later predslot
    float* cs = r;                 // [CAP] compacted scores
    int*   cp = (int*)(r + CAP);   // [CAP] compacted positions
    int*   rk = (int*)(r + 2*CAP); // [CAP] rank of compacted entry
    int*   ri = (int*)r;           // [529] inv: slot -> position (overlay, last)
    float* ps = wt;                // [CAP] pred staged by slot (overlay on weights)

    const unsigned long long ltm = (1ull << l) - 1ull;

    // ---------------- fold BN into linear weights (wave-private) ----------------
    {
        int o = l >> 3;
        float sc2o = g2[o] / sqrtf(v2[o] + 1e-5f);
        wt[24 + l] = W2[l] * sc2o;                       // w2f[64]
        if (l < 8) {
            float sc1 = g1[l] / sqrtf(v1[l] + 1e-5f);
            wt[2*l]     = W1[2*l] * sc1;                 // w1f[16]
            wt[2*l + 1] = W1[2*l + 1] * sc1;
            wt[16 + l]  = (b1[l] - m1[l]) * sc1 + be1[l];// b1f[8]
            float sc2 = g2[l] / sqrtf(v2[l] + 1e-5f);
            wt[88 + l]  = (b2[l] - m2[l]) * sc2 + be2[l];// b2f[8]
            wt[96 + l]  = W3[l];                         // w3f[8]
            if (l == 0) wt[104] = b3[0];
        }
    }

    // ---------------- issue global loads early ----------------
    const float* yrow = anno + (size_t)b * P_;
    const float* sold = tscores + (size_t)b * P_;
    const float* scur = tscores + (size_t)B * P_ + (size_t)b * P_;
    float ao[NC], so[NC], sc[NC];
    #pragma unroll
    for (int c = 0; c < NC; c++) { int p = 64*c + l; ao[c] = (p < P_) ? yrow[p] : -INFINITY; }
    #pragma unroll
    for (int c = 0; c < NC; c++) { int p = 64*c + l; so[c] = (p < P_) ? sold[p] : 0.f; }
    #pragma unroll
    for (int c = 0; c < NC; c++) { int p = 64*c + l; sc[c] = (p < P_) ? scur[p] : 0.f; }

    // ---------------- anno argmax (first max wins) ----------------
    float bv = -INFINITY; int bi = 0x7fffffff;
    #pragma unroll
    for (int c = 0; c < NC; c++) {
        int p = 64*c + l;
        if (p < P_ && ao[c] > bv) { bv = ao[c]; bi = p; }
    }
    #pragma unroll
    for (int d = 32; d > 0; d >>= 1) {
        float ov = __shfl_xor(bv, d); int oi = __shfl_xor(bi, d);
        if (ov > bv || (ov == bv && oi < bi)) { bv = ov; bi = oi; }
    }
    const int gy = bi / W_, gx = bi - (bi / W_) * W_;

    // ---------------- OLD map: peaks + stats + nearest-to-gc ----------------
    #pragma unroll
    for (int c = 0; c < NC; c++) { int p = 64*c + l; if (p < P_) m[p] = so[c]; }
    WSYNC();
    #pragma unroll
    for (int c = 0; c < NC; c++) {
        int p = 64*c + l;
        if (p < P_) {
            int y = p / W_, x = p - y * W_;
            const float* row = &m[y * W_];
            float mx = row[x];
            if (x >= 1)      mx = fmaxf(mx, row[x-1]);
            if (x >= 2)      mx = fmaxf(mx, row[x-2]);
            if (x <= W_-2)   mx = fmaxf(mx, row[x+1]);
            if (x <= W_-3)   mx = fmaxf(mx, row[x+2]);
            r[p] = mx;
        }
    }
    WSYNC();
    float So = 0.f, Mor = 0.f, Moc = 0.f;
    float nd2 = INFINITY, ns = -INFINITY; int np = 0;
    #pragma unroll
    for (int c = 0; c < NC; c++) {
        int p = 64*c + l;
        if (p < P_) {
            int y = p / W_, x = p - y * W_;
            float s = so[c];
            float sm = r[p];
            if (y >= 1)    sm = fmaxf(sm, r[p - W_]);
            if (y >= 2)    sm = fmaxf(sm, r[p - 2*W_]);
            if (y <= H_-2) sm = fmaxf(sm, r[p + W_]);
            if (y <= H_-3) sm = fmaxf(sm, r[p + 2*W_]);
            if (s == sm && s > TH_) {
                So += s; Mor += s * (float)y; Moc += s * (float)x;
                int dy = gy - y, dx = gx - x;
                float d2 = (float)(dy*dy + dx*dx);
                if (d2 < nd2 || (d2 == nd2 && (s > ns || (s == ns && p < np)))) {
                    nd2 = d2; ns = s; np = p;
                }
            }
        }
    }
    #pragma unroll
    for (int d = 32; d > 0; d >>= 1) {
        So += __shfl_xor(So, d); Mor += __shfl_xor(Mor, d); Moc += __shfl_xor(Moc, d);
        float od2 = __shfl_xor(nd2, d), os = __shfl_xor(ns, d); int op = __shfl_xor(np, d);
        if (od2 < nd2 || (od2 == nd2 && (os > ns || (os == ns && op < np)))) {
            nd2 = od2; ns = os; np = op;
        }
    }
    const int cy = np / W_, cx = np - (np / W_) * W_;
    const float foldr = So * (float)cy - Mor;   // f_old (exactly 0 when no peaks)
    const float foldc = So * (float)cx - Moc;

    // ---------------- CUR map: peaks + stats (m keeps cur scores) ----------------
    WSYNC();
    #pragma unroll
    for (int c = 0; c < NC; c++) { int p = 64*c + l; if (p < P_) m[p] = sc[c]; }
    WSYNC();
    #pragma unroll
    for (int c = 0; c < NC; c++) {
        int p = 64*c + l;
        if (p < P_) {
            int y = p / W_, x = p - y * W_;
            const float* row = &m[y * W_];
            float mx = row[x];
            if (x >= 1)      mx = fmaxf(mx, row[x-1]);
            if (x >= 2)      mx = fmaxf(mx, row[x-2]);
            if (x <= W_-2)   mx = fmaxf(mx, row[x+1]);
            if (x <= W_-3)   mx = fmaxf(mx, row[x+2]);
            r[p] = mx;
        }
    }
    WSYNC();
    float Sc = 0.f, Mcr = 0.f, Mcc = 0.f;
    int vb = 0;
    #pragma unroll
    for (int c = 0; c < NC; c++) {
        int p = 64*c + l;
        if (p < P_) {
            int y = p / W_, x = p - y * W_;
            float s = sc[c];
            float sm = r[p];
            if (y >= 1)    sm = fmaxf(sm, r[p - W_]);
            if (y >= 2)    sm = fmaxf(sm, r[p - 2*W_]);
            if (y <= H_-2) sm = fmaxf(sm, r[p + W_]);
            if (y <= H_-3) sm = fmaxf(sm, r[p + 2*W_]);
            if (s == sm && s > TH_) {
                vb |= 1 << c;
                Sc += s; Mcr += s * (float)y; Mcc += s * (float)x;
            }
        }
    }
    #pragma unroll
    for (int d = 32; d > 0; d >>= 1) {
        Sc += __shfl_xor(Sc, d); Mcr += __shfl_xor(Mcr, d); Mcc += __shfl_xor(Mcc, d);
    }
    WSYNC();   // rowmax r is dead; reuse as cs/cp/rk

    // ---------------- compaction via ballot ----------------
    int K = 0;
    int nb[NC];                       // #valid strictly before p, per chunk
    #pragma unroll
    for (int c = 0; c < NC; c++) {
        bool v = (vb >> c) & 1;
        unsigned long long bt = __ballot(v);
        int my = K + __popcll(bt & ltm);
        nb[c] = my;
        if (v && my < CAP) { cs[my] = sc[c]; cp[my] = 64*c + l; }
        K += __popcll(bt);
    }
    WSYNC();

    // ---------------- rank compacted peaks (score desc, pos asc) ----------------
    const int Kc = K > CAP ? CAP : K;
    for (int i = l; i < Kc; i += 64) {
        float si = cs[i]; int pi = cp[i]; int rr = 0;
        for (int j = 0; j < Kc; j++) {
            float sj = cs[j]; int pj = cp[j];
            rr += (sj > si || (sj == si && pj < pi)) ? 1 : 0;
        }
        rk[i] = rr;
    }
    WSYNC();

    // ---------------- MLP over compacted peaks only (<=2 passes) ----------------
    auto mlp = [&](int i, float& pv, int& rko) {
        int p = cp[i];
        float s = cs[i];
        rko = rk[i];
        int y = p / W_, x = p - (p / W_) * W_;
        float fcr = Sc * (float)y - Mcr;
        float fcc = Sc * (float)x - Mcc;
        float dr = foldr - fcr, dc = foldc - fcc;
        float err = sqrtf(fmaxf(dr*dr + dc*dc, 1e-24f));
        float h1[8];
        #pragma unroll
        for (int o = 0; o < 8; o++)
            h1[o] = fmaxf(fmaf(err, wt[2*o], fmaf(s, wt[2*o+1], wt[16+o])), 0.f);
        float pred = wt[104];
        #pragma unroll
        for (int o = 0; o < 8; o++) {
            float z = wt[88 + o];
            #pragma unroll
            for (int i2 = 0; i2 < 8; i2++) z = fmaf(h1[i2], wt[24 + o*8 + i2], z);
            pred = fmaf(fmaxf(z, 0.f), wt[96 + o], pred);
        }
        pv = pred;
    };
    float pv0 = 0.f, pv1 = 0.f; int rk0 = -1, rk1 = -1;
    if (l < Kc)      mlp(l, pv0, rk0);
    if (64 + l < Kc) mlp(64 + l, pv1, rk1);
    WSYNC();                      // all weight reads done before overlaying ps on wt
    if (rk0 >= 0 && rk0 < CAP) ps[rk0] = pv0;
    if (rk1 >= 0 && rk1 < CAP) ps[rk1] = pv1;

    // ---------------- slot per position (reads rk), then inv scatter ----------------
    int slot[NC];
    #pragma unroll
    for (int c = 0; c < NC; c++) {
        int p = 64*c + l;
        if (p < P_) {
            bool v = (vb >> c) & 1;
            int n = nb[c];
            slot[c] = v ? ((n < CAP) ? rk[n] : n) : (K + p - n);
        }
    }
    WSYNC();                      // rk reads done before ri overlays r
    #pragma unroll
    for (int c = 0; c < NC; c++) {
        int p = 64*c + l;
        if (p < P_) ri[slot[c]] = p;
    }
    WSYNC();

    // ---------------- linear, coalesced output ----------------
    const size_t BP = (size_t)B * P_;
    float* out_pred = out;
    float* out_c    = out + BP;        // [B,P,2]
    float* out_s    = out + 3 * BP;
    float* out_v    = out + 4 * BP;
    const size_t rowbase = (size_t)b * P_;

    #pragma unroll
    for (int c = 0; c < NC; c++) {
        int j = 64*c + l;
        if (j < P_) {
            int p = ri[j];
            int y = p / W_, x = p - (p / W_) * W_;
            bool val = j < K;
            float pv = (val && j < CAP) ? ps[j] : 0.f;
            float s  = m[p];
            out_pred[rowbase + j] = pv;
            ((float2*)out_c)[rowbase + j] = make_float2((float)y, (float)x);
            out_s[rowbase + j] = s;
            out_v[rowbase + j] = val ? 1.f : 0.f;
        }
    }
}

extern "C" void kernel_launch(void* const* d_in, const int* in_sizes, int n_in,
                              void* d_out, int out_size, void* d_ws, size_t ws_size,
                              hipStream_t stream) {
    const int B = in_sizes[0] / (2 * P_);
    hipLaunchKernelGGL(peak_kernel, dim3((B + WPB - 1) / WPB), dim3(NTHR), 0, stream,
        (const float*)d_in[0], (const float*)d_in[1],
        (const float*)d_in[2], (const float*)d_in[3], (const float*)d_in[4],
        (const float*)d_in[5], (const float*)d_in[6], (const float*)d_in[7],
        (const float*)d_in[8], (const float*)d_in[9], (const float*)d_in[10],
        (const float*)d_in[11], (const float*)d_in[12], (const float*)d_in[13],
        (const float*)d_in[14], (const float*)d_in[15],
        (float*)d_out, B);
}

// Round 5
// 70.842 us; speedup vs baseline: 1.0138x; 1.0138x over previous
//
#include <hip/hip_runtime.h>
#include <math.h>

#define H_   23
#define W_   23
#define P_   529
#define TH_  0.05f
#define NC   9            // ceil(529/64) chunks per wave
#define CAP  96           // max compacted peaks (geometric max is 64 for strict peaks)
#define WPB  4            // waves (batch elements) per block
#define NTHR (WPB * 64)
#define WFLO (2 * P_ + 112)  // floats per wave LDS partition

// wave-synchronous fence: per-wave LDS ops execute in program order across the
// whole wave (SIMD lockstep); this only stops compiler reordering across phases.
#define WSYNC() do { asm volatile("" ::: "memory"); __builtin_amdgcn_wave_barrier(); } while (0)

__global__ __launch_bounds__(NTHR, 8) void peak_kernel(
    const float* __restrict__ tscores,  // [2,B,P]
    const float* __restrict__ anno,     // [1,B,P]
    const float* __restrict__ W1, const float* __restrict__ b1,
    const float* __restrict__ g1, const float* __restrict__ be1,
    const float* __restrict__ m1, const float* __restrict__ v1,
    const float* __restrict__ W2, const float* __restrict__ b2,
    const float* __restrict__ g2, const float* __restrict__ be2,
    const float* __restrict__ m2, const float* __restrict__ v2,
    const float* __restrict__ W3, const float* __restrict__ b3,
    float* __restrict__ out, int B)
{
    const int t  = threadIdx.x;
    const int l  = t & 63;
    const int wv = t >> 6;
    const int b  = blockIdx.x * WPB + wv;

    __shared__ float lds[WPB * WFLO];
    float* m  = lds + wv * WFLO;   // [529] raw map (old, then cur — kept for out_s)
    float* r  = m + P_;            // [529] rowmax; later cs/cp/rk; later inv
    float* wt = r + P_;            // [112] folded MLP weights; later predslot
    float* cs = r;                 // [CAP] compacted scores
    int*   cp = (int*)(r + CAP);   // [CAP] compacted positions
    int*   rk = (int*)(r + 2*CAP); // [CAP] rank of compacted entry
    int*   ri = (int*)r;           // [529] inv: slot -> position (overlay, last)
    float* ps = wt;                // [CAP] pred staged by slot (overlay on weights)

    const unsigned long long ltm = (1ull << l) - 1ull;

    // ---------------- fold BN into linear weights (wave-private) ----------------
    {
        int o = l >> 3;
        float sc2o = g2[o] / sqrtf(v2[o] + 1e-5f);
        wt[24 + l] = W2[l] * sc2o;                       // w2f[64]
        if (l < 8) {
            float sc1 = g1[l] / sqrtf(v1[l] + 1e-5f);
            wt[2*l]     = W1[2*l] * sc1;                 // w1f[16]
            wt[2*l + 1] = W1[2*l + 1] * sc1;
            wt[16 + l]  = (b1[l] - m1[l]) * sc1 + be1[l];// b1f[8]
            float sc2 = g2[l] / sqrtf(v2[l] + 1e-5f);
            wt[88 + l]  = (b2[l] - m2[l]) * sc2 + be2[l];// b2f[8]
            wt[96 + l]  = W3[l];                         // w3f[8]
            if (l == 0) wt[104] = b3[0];
        }
    }

    // ---------------- issue global loads early ----------------
    const float* yrow = anno + (size_t)b * P_;
    const float* sold = tscores + (size_t)b * P_;
    const float* scur = tscores + (size_t)B * P_ + (size_t)b * P_;
    float ao[NC], so[NC], sc[NC];
    #pragma unroll
    for (int c = 0; c < NC; c++) { int p = 64*c + l; ao[c] = (p < P_) ? yrow[p] : -INFINITY; }
    #pragma unroll
    for (int c = 0; c < NC; c++) { int p = 64*c + l; so[c] = (p < P_) ? sold[p] : 0.f; }
    #pragma unroll
    for (int c = 0; c < NC; c++) { int p = 64*c + l; sc[c] = (p < P_) ? scur[p] : 0.f; }

    // ---------------- anno argmax (first max wins) ----------------
    float bv = -INFINITY; int bi = 0x7fffffff;
    #pragma unroll
    for (int c = 0; c < NC; c++) {
        int p = 64*c + l;
        if (p < P_ && ao[c] > bv) { bv = ao[c]; bi = p; }
    }
    #pragma unroll
    for (int d = 32; d > 0; d >>= 1) {
        float ov = __shfl_xor(bv, d); int oi = __shfl_xor(bi, d);
        if (ov > bv || (ov == bv && oi < bi)) { bv = ov; bi = oi; }
    }
    const int gy = bi / W_, gx = bi - (bi / W_) * W_;

    // ---------------- OLD map: peaks + stats + nearest-to-gc ----------------
    #pragma unroll
    for (int c = 0; c < NC; c++) { int p = 64*c + l; if (p < P_) m[p] = so[c]; }
    WSYNC();
    #pragma unroll
    for (int c = 0; c < NC; c++) {
        int p = 64*c + l;
        if (p < P_) {
            int y = p / W_, x = p - y * W_;
            const float* row = &m[y * W_];
            float mx = row[x];
            if (x >= 1)      mx = fmaxf(mx, row[x-1]);
            if (x >= 2)      mx = fmaxf(mx, row[x-2]);
            if (x <= W_-2)   mx = fmaxf(mx, row[x+1]);
            if (x <= W_-3)   mx = fmaxf(mx, row[x+2]);
            r[p] = mx;
        }
    }
    WSYNC();
    float So = 0.f, Mor = 0.f, Moc = 0.f;
    float nd2 = INFINITY, ns = -INFINITY; int np = 0;
    #pragma unroll
    for (int c = 0; c < NC; c++) {
        int p = 64*c + l;
        if (p < P_) {
            int y = p / W_, x = p - y * W_;
            float s = so[c];
            float sm = r[p];
            if (y >= 1)    sm = fmaxf(sm, r[p - W_]);
            if (y >= 2)    sm = fmaxf(sm, r[p - 2*W_]);
            if (y <= H_-2) sm = fmaxf(sm, r[p + W_]);
            if (y <= H_-3) sm = fmaxf(sm, r[p + 2*W_]);
            if (s == sm && s > TH_) {
                So += s; Mor += s * (float)y; Moc += s * (float)x;
                int dy = gy - y, dx = gx - x;
                float d2 = (float)(dy*dy + dx*dx);
                if (d2 < nd2 || (d2 == nd2 && (s > ns || (s == ns && p < np)))) {
                    nd2 = d2; ns = s; np = p;
                }
            }
        }
    }
    #pragma unroll
    for (int d = 32; d > 0; d >>= 1) {
        So += __shfl_xor(So, d); Mor += __shfl_xor(Mor, d); Moc += __shfl_xor(Moc, d);
        float od2 = __shfl_xor(nd2, d), os = __shfl_xor(ns, d); int op = __shfl_xor(np, d);
        if (od2 < nd2 || (od2 == nd2 && (os > ns || (os == ns && op < np)))) {
            nd2 = od2; ns = os; np = op;
        }
    }
    const int cy = np / W_, cx = np - (np / W_) * W_;
    const float foldr = So * (float)cy - Mor;   // f_old (exactly 0 when no peaks)
    const float foldc = So * (float)cx - Moc;

    // ---------------- CUR map: peaks + stats (m keeps cur scores) ----------------
    WSYNC();
    #pragma unroll
    for (int c = 0; c < NC; c++) { int p = 64*c + l; if (p < P_) m[p] = sc[c]; }
    WSYNC();
    #pragma unroll
    for (int c = 0; c < NC; c++) {
        int p = 64*c + l;
        if (p < P_) {
            int y = p / W_, x = p - y * W_;
            const float* row = &m[y * W_];
            float mx = row[x];
            if (x >= 1)      mx = fmaxf(mx, row[x-1]);
            if (x >= 2)      mx = fmaxf(mx, row[x-2]);
            if (x <= W_-2)   mx = fmaxf(mx, row[x+1]);
            if (x <= W_-3)   mx = fmaxf(mx, row[x+2]);
            r[p] = mx;
        }
    }
    WSYNC();
    float Sc = 0.f, Mcr = 0.f, Mcc = 0.f;
    int vb = 0;
    #pragma unroll
    for (int c = 0; c < NC; c++) {
        int p = 64*c + l;
        if (p < P_) {
            int y = p / W_, x = p - y * W_;
            float s = sc[c];
            float sm = r[p];
            if (y >= 1)    sm = fmaxf(sm, r[p - W_]);
            if (y >= 2)    sm = fmaxf(sm, r[p - 2*W_]);
            if (y <= H_-2) sm = fmaxf(sm, r[p + W_]);
            if (y <= H_-3) sm = fmaxf(sm, r[p + 2*W_]);
            if (s == sm && s > TH_) {
                vb |= 1 << c;
                Sc += s; Mcr += s * (float)y; Mcc += s * (float)x;
            }
        }
    }
    #pragma unroll
    for (int d = 32; d > 0; d >>= 1) {
        Sc += __shfl_xor(Sc, d); Mcr += __shfl_xor(Mcr, d); Mcc += __shfl_xor(Mcc, d);
    }
    WSYNC();   // rowmax r is dead; reuse as cs/cp/rk

    // ---------------- compaction via ballot ----------------
    int K = 0;
    int nb[NC];                       // #valid strictly before p, per chunk
    #pragma unroll
    for (int c = 0; c < NC; c++) {
        bool v = (vb >> c) & 1;
        unsigned long long bt = __ballot(v);
        int my = K + __popcll(bt & ltm);
        nb[c] = my;
        if (v && my < CAP) { cs[my] = sc[c]; cp[my] = 64*c + l; }
        K += __popcll(bt);
    }
    WSYNC();

    // ---------------- rank compacted peaks (score desc, pos asc) ----------------
    const int Kc = K > CAP ? CAP : K;
    for (int i = l; i < Kc; i += 64) {
        float si = cs[i]; int pi = cp[i]; int rr = 0;
        for (int j = 0; j < Kc; j++) {
            float sj = cs[j]; int pj = cp[j];
            rr += (sj > si || (sj == si && pj < pi)) ? 1 : 0;
        }
        rk[i] = rr;
    }
    WSYNC();

    // ---------------- MLP over compacted peaks only (<=2 passes) ----------------
    auto mlp = [&](int i, float& pv, int& rko) {
        int p = cp[i];
        float s = cs[i];
        rko = rk[i];
        int y = p / W_, x = p - (p / W_) * W_;
        float fcr = Sc * (float)y - Mcr;
        float fcc = Sc * (float)x - Mcc;
        float dr = foldr - fcr, dc = foldc - fcc;
        float err = sqrtf(fmaxf(dr*dr + dc*dc, 1e-24f));
        float h1[8];
        #pragma unroll
        for (int o = 0; o < 8; o++)
            h1[o] = fmaxf(fmaf(err, wt[2*o], fmaf(s, wt[2*o+1], wt[16+o])), 0.f);
        float pred = wt[104];
        #pragma unroll
        for (int o = 0; o < 8; o++) {
            float z = wt[88 + o];
            #pragma unroll
            for (int i2 = 0; i2 < 8; i2++) z = fmaf(h1[i2], wt[24 + o*8 + i2], z);
            pred = fmaf(fmaxf(z, 0.f), wt[96 + o], pred);
        }
        pv = pred;
    };
    float pv0 = 0.f, pv1 = 0.f; int rk0 = -1, rk1 = -1;
    if (l < Kc)      mlp(l, pv0, rk0);
    if (64 + l < Kc) mlp(64 + l, pv1, rk1);
    WSYNC();                      // all weight reads done before overlaying ps on wt
    if (rk0 >= 0 && rk0 < CAP) ps[rk0] = pv0;
    if (rk1 >= 0 && rk1 < CAP) ps[rk1] = pv1;

    // ---------------- slot per position (reads rk), then inv scatter ----------------
    int slot[NC];
    #pragma unroll
    for (int c = 0; c < NC; c++) {
        int p = 64*c + l;
        if (p < P_) {
            bool v = (vb >> c) & 1;
            int n = nb[c];
            slot[c] = v ? ((n < CAP) ? rk[n] : n) : (K + p - n);
        }
    }
    WSYNC();                      // rk reads done before ri overlays r
    #pragma unroll
    for (int c = 0; c < NC; c++) {
        int p = 64*c + l;
        if (p < P_) ri[slot[c]] = p;
    }
    WSYNC();

    // ---------------- linear, coalesced output ----------------
    const size_t BP = (size_t)B * P_;
    float* out_pred = out;
    float* out_c    = out + BP;        // [B,P,2]
    float* out_s    = out + 3 * BP;
    float* out_v    = out + 4 * BP;
    const size_t rowbase = (size_t)b * P_;

    #pragma unroll
    for (int c = 0; c < NC; c++) {
        int j = 64*c + l;
        if (j < P_) {
            int p = ri[j];
            int y = p / W_, x = p - (p / W_) * W_;
            bool val = j < K;
            float pv = (val && j < CAP) ? ps[j] : 0.f;
            float s  = m[p];
            out_pred[rowbase + j] = pv;
            ((float2*)out_c)[rowbase + j] = make_float2((float)y, (float)x);
            out_s[rowbase + j] = s;
            out_v[rowbase + j] = val ? 1.f : 0.f;
        }
    }
}

extern "C" void kernel_launch(void* const* d_in, const int* in_sizes, int n_in,
                              void* d_out, int out_size, void* d_ws, size_t ws_size,
                              hipStream_t stream) {
    const int B = in_sizes[0] / (2 * P_);
    hipLaunchKernelGGL(peak_kernel, dim3((B + WPB - 1) / WPB), dim3(NTHR), 0, stream,
        (const float*)d_in[0], (const float*)d_in[1],
        (const float*)d_in[2], (const float*)d_in[3], (const float*)d_in[4],
        (const float*)d_in[5], (const float*)d_in[6], (const float*)d_in[7],
        (const float*)d_in[8], (const float*)d_in[9], (const float*)d_in[10],
        (const float*)d_in[11], (const float*)d_in[12], (const float*)d_in[13],
        (const float*)d_in[14], (const float*)d_in[15],
        (float*)d_out, B);
}